// Round 5
// baseline (154.677 us; speedup 1.0000x reference)
//
#include <hip/hip_runtime.h>

#define BB 8
#define NN 4096
#define TPB 256
#define TI 64                    // rows per block
#define WR (TI / 4)              // 16 rows per wave
#define NCB 4                    // column blocks (1024 cols each)
#define WCOL 1024                // cols per block window
#define NRB (NN / TI)            // 64 row-blocks per batch

// ws layout (floats):
//   q:      [BB*NN*3]        offset 0        (98304)
//   neighp: [NCB*BB*NN*3]    offset 98304    (393216)  (atomic mode: [BB*NN*3])
//   degp:   [BB*NRB*NN]      offset 491520   (2097152) (atomic mode: [BB*NN])
// partial-mode total ~10.4 MB

__global__ __launch_bounds__(256) void k_init(const float* __restrict__ p1,
                                              const float* __restrict__ p2,
                                              float* __restrict__ q,
                                              float* __restrict__ neighp,
                                              float* __restrict__ degp,
                                              float* __restrict__ out,
                                              int atomic_mode) {
    int i = blockIdx.x * 256 + threadIdx.x;
    if (i < BB * NN * 3) q[i] = p2[i] - p1[i];
    if (atomic_mode) {
        if (i < BB * NN * 3) neighp[i] = 0.0f;
        if (i < BB * NN) degp[i] = 0.0f;
    }
    if (i == 0) out[0] = 0.0f;
}

__global__ __launch_bounds__(TPB, 4) void k_main(const float* __restrict__ A,
                                                 const float* __restrict__ q,
                                                 float* __restrict__ neighp,
                                                 float* __restrict__ degp,
                                                 int atomic_mode) {
    __shared__ float lds_n[TI * 3];     // per-row neigh partials (this col window)
    __shared__ float dcomb[WCOL];       // transposed deg combine: [j&3][col>>2]

    const int tid  = threadIdx.x;
    const int lane = tid & 63;
    const int w    = tid >> 6;

    int bid = blockIdx.x;
    const int cb = bid & (NCB - 1); bid >>= 2;
    const int rb = bid % NRB;
    const int b  = bid / NRB;

    const int ro = rb * TI + w * WR;    // this wave's first row
    const float* Ab  = A + (size_t)b * NN * NN;
    const float* qbp = q + (size_t)b * NN * 3;

    for (int t = tid; t < WCOL; t += TPB) dcomb[t] = 0.0f;
    __syncthreads();

    // this lane's 4 column groups: col[k] = cb*1024 + k*256 + lane*4
    int col[4];
    float4 qa[4], qm[4], qc[4];
#pragma unroll
    for (int k = 0; k < 4; ++k) {
        col[k] = cb * WCOL + k * 256 + lane * 4;
        const float* qp = qbp + (size_t)col[k] * 3;   // 48B-aligned
        qa[k] = *(const float4*)(qp);
        qm[k] = *(const float4*)(qp + 4);
        qc[k] = *(const float4*)(qp + 8);
        // cols c0..c3: c0=(qa.x,qa.y,qa.z) c1=(qa.w,qm.x,qm.y)
        //              c2=(qm.z,qm.w,qc.x) c3=(qc.y,qc.z,qc.w)
    }

    float4 dg[4];
#pragma unroll
    for (int k = 0; k < 4; ++k) dg[k] = make_float4(0.f, 0.f, 0.f, 0.f);

#pragma unroll 2
    for (int r = 0; r < WR; ++r) {
        const float* Ar = Ab + (size_t)(ro + r) * NN;
        float n0 = 0.f, n1 = 0.f, n2 = 0.f;
#pragma unroll
        for (int k = 0; k < 4; ++k) {
            const float4 a = *(const float4*)(Ar + col[k]);
            dg[k].x += a.x; dg[k].y += a.y; dg[k].z += a.z; dg[k].w += a.w;
            n0 += a.x * qa[k].x + a.y * qa[k].w + a.z * qm[k].z + a.w * qc[k].y;
            n1 += a.x * qa[k].y + a.y * qm[k].x + a.z * qm[k].w + a.w * qc[k].z;
            n2 += a.x * qa[k].z + a.y * qm[k].y + a.z * qc[k].x + a.w * qc[k].w;
        }
        // one 64-lane butterfly per 4 KB of A (amortized 4x vs prev round)
#pragma unroll
        for (int s = 1; s < 64; s <<= 1) {
            n0 += __shfl_xor(n0, s, 64);
            n1 += __shfl_xor(n1, s, 64);
            n2 += __shfl_xor(n2, s, 64);
        }
        if (atomic_mode) {
            if (lane == 0) {
                float* np = neighp + ((size_t)b * NN + ro + r) * 3;
                atomicAdd(&np[0], n0);
                atomicAdd(&np[1], n1);
                atomicAdd(&np[2], n2);
            }
        } else if (lane == 0) {
            lds_n[(w * WR + r) * 3 + 0] = n0;
            lds_n[(w * WR + r) * 3 + 1] = n1;
            lds_n[(w * WR + r) * 3 + 2] = n2;
        }
    }

    // deg: combine the 4 waves' register partials
    if (atomic_mode) {
        float* dp = degp + (size_t)b * NN;
#pragma unroll
        for (int k = 0; k < 4; ++k) {
            atomicAdd(&dp[col[k] + 0], dg[k].x);
            atomicAdd(&dp[col[k] + 1], dg[k].y);
            atomicAdd(&dp[col[k] + 2], dg[k].z);
            atomicAdd(&dp[col[k] + 3], dg[k].w);
        }
    } else {
#pragma unroll
        for (int k = 0; k < 4; ++k) {
            const int c4 = k * 64 + lane;      // (local col)>>2 ; bank = lane%32 (2-way, free)
            atomicAdd(&dcomb[0 * 256 + c4], dg[k].x);
            atomicAdd(&dcomb[1 * 256 + c4], dg[k].y);
            atomicAdd(&dcomb[2 * 256 + c4], dg[k].z);
            atomicAdd(&dcomb[3 * 256 + c4], dg[k].w);
        }
    }

    __syncthreads();
    if (!atomic_mode) {
        if (tid < TI * 3) {
            neighp[((size_t)(cb * BB + b) * NN + rb * TI) * 3 + tid] = lds_n[tid];
        }
        float* dp = degp + ((size_t)b * NRB + rb) * NN + cb * WCOL;
#pragma unroll
        for (int t = tid; t < WCOL; t += TPB) {
            dp[t] = dcomb[(t & 3) * 256 + (t >> 2)];
        }
    }
}

// 512 blocks x 256 threads; block handles 64 rows; 4 waves each sum a quarter
// of the deg slabs, LDS-combine, then wave 0 finishes the loss.
__global__ __launch_bounds__(256) void k_final(const float* __restrict__ q,
                                               const float* __restrict__ neighp,
                                               const float* __restrict__ degp,
                                               int nslab, int ncb,
                                               float* __restrict__ out) {
    __shared__ float dred[4][64];
    const int lane = threadIdx.x & 63;
    const int qi   = threadIdx.x >> 6;
    const int R    = blockIdx.x * 64 + lane;      // global row in [0, BB*NN)
    const int b    = R / NN;
    const int i    = R - b * NN;

    const float* dp = degp + ((size_t)b * nslab) * NN + i;
    float a0 = 0.f;
    for (int s = qi; s < nslab; s += 4) a0 += dp[(size_t)s * NN];
    dred[qi][lane] = a0;
    __syncthreads();

    if (qi == 0) {
        const float deg = dred[0][lane] + dred[1][lane] + dred[2][lane] + dred[3][lane];
        const float inv = 1.0f / deg;

        float nd0 = 0.f, nd1 = 0.f, nd2 = 0.f;
        for (int cbi = 0; cbi < ncb; ++cbi) {
            const float* np = neighp + ((size_t)(cbi * BB + b) * NN + i) * 3;
            nd0 += np[0]; nd1 += np[1]; nd2 += np[2];
        }

        const float c0 = q[(size_t)R * 3 + 0] - nd0 * inv;
        const float c1 = q[(size_t)R * 3 + 1] - nd1 * inv;
        const float c2 = q[(size_t)R * 3 + 2] - nd2 * inv;
        float acc = c0 * c0 + c1 * c1 + c2 * c2;
#pragma unroll
        for (int sft = 32; sft > 0; sft >>= 1) acc += __shfl_down(acc, sft, 64);
        if (lane == 0) atomicAdd(out, acc);
    }
}

extern "C" void kernel_launch(void* const* d_in, const int* in_sizes, int n_in,
                              void* d_out, int out_size, void* d_ws, size_t ws_size,
                              hipStream_t stream) {
    const float* pred1 = (const float*)d_in[0];
    const float* pred2 = (const float*)d_in[1];
    const float* A     = (const float*)d_in[2];
    float* out = (float*)d_out;

    float* q      = (float*)d_ws;
    float* neighp = q + (size_t)BB * NN * 3;
    float* degp   = neighp + (size_t)NCB * BB * NN * 3;

    const size_t need_partial =
        ((size_t)BB * NN * 3 + (size_t)NCB * BB * NN * 3 + (size_t)BB * NRB * NN) *
        sizeof(float);
    const int atomic_mode = (ws_size < need_partial) ? 1 : 0;
    const int nslab = atomic_mode ? 1 : NRB;
    const int ncb   = atomic_mode ? 1 : NCB;

    k_init<<<(BB * NN * 3 + 255) / 256, 256, 0, stream>>>(pred1, pred2, q, neighp,
                                                          degp, out, atomic_mode);
    k_main<<<BB * NRB * NCB, TPB, 0, stream>>>(A, q, neighp, degp, atomic_mode);
    k_final<<<(BB * NN) / 64, 256, 0, stream>>>(q, neighp, degp, nslab, ncb, out);
}

// Round 6
// 119.565 us; speedup vs baseline: 1.2937x; 1.2937x over previous
//
#include <hip/hip_runtime.h>

#define BB 8
#define NN 4096
#define TPB 256
#define NCB 32           // column strips of 128 cols
#define SC 128           // cols per strip
#define NRB 4            // row blocks
#define RR 1024          // rows per block
#define TSTEPS (RR / 16) // 64
#define NDSLAB (NRB * 4) // deg slabs: (rb, wave)

// ws layout (floats):
//   q:      [BB*NN*3]          offset 0       (98304)
//   neighp: [NCB*BB*NN*3]      offset 98304   (3145728)   (atomic: [BB*NN*3])
//   degp:   [NDSLAB*BB*NN]     offset 3244032 (524288)    (atomic: [BB*NN])
// partial-mode total ~14.4 MB

__global__ __launch_bounds__(256) void k_init(const float* __restrict__ p1,
                                              const float* __restrict__ p2,
                                              float* __restrict__ q,
                                              float* __restrict__ neighp,
                                              float* __restrict__ degp,
                                              float* __restrict__ out,
                                              int atomic_mode) {
    int i = blockIdx.x * 256 + threadIdx.x;
    if (i < BB * NN * 3) q[i] = p2[i] - p1[i];
    if (atomic_mode) {
        if (i < BB * NN * 3) neighp[i] = 0.0f;
        if (i < BB * NN) degp[i] = 0.0f;
    }
    if (i == 0) out[0] = 0.0f;
}

__global__ __launch_bounds__(TPB, 4) void k_main(const float* __restrict__ A,
                                                 const float* __restrict__ q,
                                                 float* __restrict__ neighp,
                                                 float* __restrict__ degp,
                                                 int atomic_mode) {
    const int lane = threadIdx.x & 63;
    const int w    = threadIdx.x >> 6;   // wave 0..3
    const int rs   = lane >> 4;          // row sub-slot 0..3
    const int cq   = lane & 15;          // col-octet 0..15

    int bid = blockIdx.x;
    const int cb = bid & (NCB - 1); bid >>= 5;
    const int rb = bid & (NRB - 1); bid >>= 2;
    const int b  = bid;                  // 0..7

    const int col  = cb * SC + cq * 8;   // lane's 8 fixed columns
    const int row0 = rb * RR + w * 4 + rs;

    // q for the 8 fixed columns: 24 floats, loaded once (byte off % 96 -> 16B aligned)
    const float* qp = q + (size_t)b * NN * 3 + (size_t)col * 3;
    const float4 v0 = *(const float4*)(qp + 0);
    const float4 v1 = *(const float4*)(qp + 4);
    const float4 v2 = *(const float4*)(qp + 8);
    const float4 v3 = *(const float4*)(qp + 12);
    const float4 v4 = *(const float4*)(qp + 16);
    const float4 v5 = *(const float4*)(qp + 20);
    // c0=(v0.x,v0.y,v0.z) c1=(v0.w,v1.x,v1.y) c2=(v1.z,v1.w,v2.x) c3=(v2.y,v2.z,v2.w)
    // c4=(v3.x,v3.y,v3.z) c5=(v3.w,v4.x,v4.y) c6=(v4.z,v4.w,v5.x) c7=(v5.y,v5.z,v5.w)

    const float* Ap = A + (size_t)b * NN * NN + (size_t)row0 * NN + col;

    float4 dgA = make_float4(0.f, 0.f, 0.f, 0.f);
    float4 dgB = make_float4(0.f, 0.f, 0.f, 0.f);

    float* npbase = atomic_mode ? (neighp + (size_t)b * NN * 3)
                                : (neighp + (size_t)(cb * BB + b) * NN * 3);

#pragma unroll 2
    for (int t = 0; t < TSTEPS; ++t) {
        const float4 a1 = *(const float4*)(Ap);
        const float4 a2 = *(const float4*)(Ap + 4);
        Ap += (size_t)16 * NN;

        dgA.x += a1.x; dgA.y += a1.y; dgA.z += a1.z; dgA.w += a1.w;
        dgB.x += a2.x; dgB.y += a2.y; dgB.z += a2.z; dgB.w += a2.w;

        float n0 = a1.x * v0.x + a1.y * v0.w + a1.z * v1.z + a1.w * v2.y +
                   a2.x * v3.x + a2.y * v3.w + a2.z * v4.z + a2.w * v5.y;
        float n1 = a1.x * v0.y + a1.y * v1.x + a1.z * v1.w + a1.w * v2.z +
                   a2.x * v3.y + a2.y * v4.x + a2.z * v4.w + a2.w * v5.z;
        float n2 = a1.x * v0.z + a1.y * v1.y + a1.z * v2.x + a1.w * v2.w +
                   a2.x * v3.z + a2.y * v4.y + a2.z * v5.x + a2.w * v5.w;

        // reduce across the 16-lane column group (one row per group)
#pragma unroll
        for (int s = 1; s < 16; s <<= 1) {
            n0 += __shfl_xor(n0, s, 64);
            n1 += __shfl_xor(n1, s, 64);
            n2 += __shfl_xor(n2, s, 64);
        }
        if (cq == 0) {
            const int row = row0 + t * 16;
            float* p = npbase + (size_t)row * 3;
            if (atomic_mode) {
                atomicAdd(&p[0], n0); atomicAdd(&p[1], n1); atomicAdd(&p[2], n2);
            } else {
                p[0] = n0; p[1] = n1; p[2] = n2;
            }
        }
    }

    // combine deg across the 4 row sub-slots (lanes l, l^16, l^32, l^48)
#pragma unroll
    for (int s = 16; s < 64; s <<= 1) {
        dgA.x += __shfl_xor(dgA.x, s, 64); dgA.y += __shfl_xor(dgA.y, s, 64);
        dgA.z += __shfl_xor(dgA.z, s, 64); dgA.w += __shfl_xor(dgA.w, s, 64);
        dgB.x += __shfl_xor(dgB.x, s, 64); dgB.y += __shfl_xor(dgB.y, s, 64);
        dgB.z += __shfl_xor(dgB.z, s, 64); dgB.w += __shfl_xor(dgB.w, s, 64);
    }
    if (rs == 0) {   // 16 lanes, contiguous 128B per wave
        if (atomic_mode) {
            float* dp = degp + (size_t)b * NN + col;
            atomicAdd(&dp[0], dgA.x); atomicAdd(&dp[1], dgA.y);
            atomicAdd(&dp[2], dgA.z); atomicAdd(&dp[3], dgA.w);
            atomicAdd(&dp[4], dgB.x); atomicAdd(&dp[5], dgB.y);
            atomicAdd(&dp[6], dgB.z); atomicAdd(&dp[7], dgB.w);
        } else {
            float* dp = degp + ((size_t)(rb * 4 + w) * BB + b) * NN + col;
            *(float4*)(dp + 0) = dgA;
            *(float4*)(dp + 4) = dgB;
        }
    }
}

// 512 blocks x 256 threads; wave qi sums strips/slabs qi::4; LDS-combine;
// wave 0 finishes the loss for its 64 rows.
__global__ __launch_bounds__(256) void k_final(const float* __restrict__ q,
                                               const float* __restrict__ neighp,
                                               const float* __restrict__ degp,
                                               int nslab, int ncb,
                                               float* __restrict__ out) {
    __shared__ float dredN[4][64][3];
    __shared__ float dredD[4][64];
    const int lane = threadIdx.x & 63;
    const int qi   = threadIdx.x >> 6;
    const int R    = blockIdx.x * 64 + lane;   // global row in [0, BB*NN)
    const int b    = R / NN;
    const int i    = R - b * NN;

    float n0 = 0.f, n1 = 0.f, n2 = 0.f;
    for (int c = qi; c < ncb; c += 4) {
        const float* p = neighp + ((size_t)(c * BB + b) * NN + i) * 3;
        n0 += p[0]; n1 += p[1]; n2 += p[2];
    }
    dredN[qi][lane][0] = n0; dredN[qi][lane][1] = n1; dredN[qi][lane][2] = n2;

    float d0 = 0.f;
    for (int s = qi; s < nslab; s += 4)
        d0 += degp[((size_t)s * BB + b) * NN + i];
    dredD[qi][lane] = d0;
    __syncthreads();

    if (qi == 0) {
        const float deg = dredD[0][lane] + dredD[1][lane] + dredD[2][lane] + dredD[3][lane];
        const float inv = 1.0f / deg;
        const float nd0 = dredN[0][lane][0] + dredN[1][lane][0] + dredN[2][lane][0] + dredN[3][lane][0];
        const float nd1 = dredN[0][lane][1] + dredN[1][lane][1] + dredN[2][lane][1] + dredN[3][lane][1];
        const float nd2 = dredN[0][lane][2] + dredN[1][lane][2] + dredN[2][lane][2] + dredN[3][lane][2];

        const float c0 = q[(size_t)R * 3 + 0] - nd0 * inv;
        const float c1 = q[(size_t)R * 3 + 1] - nd1 * inv;
        const float c2 = q[(size_t)R * 3 + 2] - nd2 * inv;
        float acc = c0 * c0 + c1 * c1 + c2 * c2;
#pragma unroll
        for (int sft = 32; sft > 0; sft >>= 1) acc += __shfl_down(acc, sft, 64);
        if (lane == 0) atomicAdd(out, acc);
    }
}

extern "C" void kernel_launch(void* const* d_in, const int* in_sizes, int n_in,
                              void* d_out, int out_size, void* d_ws, size_t ws_size,
                              hipStream_t stream) {
    const float* pred1 = (const float*)d_in[0];
    const float* pred2 = (const float*)d_in[1];
    const float* A     = (const float*)d_in[2];
    float* out = (float*)d_out;

    float* q      = (float*)d_ws;
    float* neighp = q + (size_t)BB * NN * 3;
    float* degp   = neighp + (size_t)NCB * BB * NN * 3;

    const size_t need_partial =
        ((size_t)BB * NN * 3 + (size_t)NCB * BB * NN * 3 + (size_t)NDSLAB * BB * NN) *
        sizeof(float);
    const int atomic_mode = (ws_size < need_partial) ? 1 : 0;
    const int nslab = atomic_mode ? 1 : NDSLAB;
    const int ncb   = atomic_mode ? 1 : NCB;

    k_init<<<(BB * NN * 3 + 255) / 256, 256, 0, stream>>>(pred1, pred2, q, neighp,
                                                          degp, out, atomic_mode);
    k_main<<<BB * NRB * NCB, TPB, 0, stream>>>(A, q, neighp, degp, atomic_mode);
    k_final<<<(BB * NN) / 64, 256, 0, stream>>>(q, neighp, degp, nslab, ncb, out);
}